// Round 5
// baseline (80.576 us; speedup 1.0000x reference)
//
#include <hip/hip_runtime.h>
#include <stdint.h>

#define NBINS 313
#define NBQ   320        // padded to a multiple of 8 for clean unroll
#define HW    65536      // 256*256
#define NPIX  (4 * HW)   // 262144
#define QTR   (NPIX / 4) // 65536
#define TPB   128
#define NBLK  (QTR / TPB) // 512

// Kernel 1: per-pixel NN weight + weighted L2, block partial sums -> d_ws.
// Key trick: f = (0.5|g|^2 + 12) - g.t lies in [10.28, 14.46] (one binade,
// [8,16)), so sign+exponent bits are constant and (bits(f)<<9)|q is an exact
// order-preserving key on the full mantissa; ties -> smallest q (jnp.argmin
// semantics). Padding bins get f = 15.9 (same binade, > max real f).
__global__ __launch_bounds__(TPB) void loss_main(
    const float* __restrict__ input, const float* __restrict__ target,
    const float* __restrict__ ab, const float* __restrict__ prior,
    float* __restrict__ partials)
{
    __shared__ float4 s_bins[NBQ];   // {gx, gy, 0.5*|g|^2 + 12, 0}
    __shared__ float  s_w[NBQ];
    const int tid = threadIdx.x;

    for (int i = tid; i < NBQ; i += TPB) {
        float gx = 0.0f, gy = 0.0f, z = 15.9f, w = 0.0f;
        if (i < NBINS) {
            gx = ab[2 * i];
            gy = ab[2 * i + 1];
            z  = fmaf(0.5f * gx, gx, fmaf(0.5f * gy, gy, 12.0f));
            w  = prior[i];
        }
        s_bins[i] = make_float4(gx, gy, z, 0.0f);
        s_w[i] = w;
    }
    __syncthreads();

    // 4 pixels per thread, one from each quarter (coalesced per quarter)
    const int base = blockIdx.x * TPB + tid;

    float tx[4], ty[4], d2[4];
#pragma unroll
    for (int k = 0; k < 4; ++k) {
        const int p  = base + k * QTR;
        const int i0 = p + (p & ~(HW - 1));   // channel-0 flat index
        const int i1 = i0 + HW;               // channel-1
        const float txx = target[i0], tyy = target[i1];
        const float axx = input[i0],  ayy = input[i1];
        const float dx = axx - txx, dy = ayy - tyy;
        tx[k] = txx; ty[k] = tyy;
        d2[k] = dx * dx + dy * dy;
    }

    uint32_t u[4] = {0xFFFFFFFFu, 0xFFFFFFFFu, 0xFFFFFFFFu, 0xFFFFFFFFu};
#pragma unroll 8
    for (int q = 0; q < NBQ; ++q) {
        const float4 bn = s_bins[q];
#pragma unroll
        for (int k = 0; k < 4; ++k) {
            const float f = fmaf(-bn.x, tx[k], fmaf(-bn.y, ty[k], bn.z));
            const uint32_t v = (__float_as_uint(f) << 9) | (uint32_t)q;
            u[k] = v < u[k] ? v : u[k];
        }
    }

    float sum = 0.0f;
#pragma unroll
    for (int k = 0; k < 4; ++k)
        sum = fmaf(d2[k], s_w[u[k] & 511u], sum);

    // wave (64) reduce, then cross-wave via LDS
    for (int off = 32; off > 0; off >>= 1)
        sum += __shfl_down(sum, off);

    __shared__ float s_part[TPB / 64];
    if ((tid & 63) == 0) s_part[tid >> 6] = sum;
    __syncthreads();
    if (tid == 0) {
        float acc = 0.0f;
#pragma unroll
        for (int wv = 0; wv < TPB / 64; ++wv) acc += s_part[wv];
        partials[blockIdx.x] = acc;
    }
}

// Kernel 2: reduce 512 partials -> scalar loss (mean over batch: *0.25)
__global__ __launch_bounds__(64) void loss_reduce(
    const float* __restrict__ partials, float* __restrict__ out)
{
    const int tid = threadIdx.x;
    float s = 0.0f;
    for (int i = tid; i < NBLK; i += 64) s += partials[i];
    for (int off = 32; off > 0; off >>= 1)
        s += __shfl_down(s, off);
    if (tid == 0) out[0] = 0.25f * s;
}

extern "C" void kernel_launch(void* const* d_in, const int* in_sizes, int n_in,
                              void* d_out, int out_size, void* d_ws, size_t ws_size,
                              hipStream_t stream)
{
    const float* input  = (const float*)d_in[0];
    const float* target = (const float*)d_in[1];
    const float* ab     = (const float*)d_in[2];
    const float* prior  = (const float*)d_in[3];
    float* out      = (float*)d_out;
    float* partials = (float*)d_ws;

    loss_main<<<NBLK, TPB, 0, stream>>>(input, target, ab, prior, partials);
    loss_reduce<<<1, 64, 0, stream>>>(partials, out);
}